// Round 3
// baseline (249.016 us; speedup 1.0000x reference)
//
#include <hip/hip_runtime.h>

// out[n,c,p,y,x] = in1[n,c,y,x] - zpad(in2)[n,c, y+i-3, x+j-3],  p = i*7+j
// N=8, C=32, H=W=112, K=7, pad=3 -> out [8,32,49,112,112] fp32 (629 MB).
//
// R2: block b owns OUTPUT PLANE b (flat plane index = nc*49+p). Concurrent
// blocks (consecutive b) therefore write consecutive 200 KB regions -> the
// device-wide instantaneous write window is a narrow (~30 MB) monotonically
// sweeping range, matching the fill kernel's pattern (6.8 TB/s calibration).
// Plain write-allocate stores (R1's nontemporal stores regressed 134->172).

#define NC_TOT 256        // 8*32
#define HW     112
#define PLANE  12544      // 112*112
#define KK     49

typedef float f4 __attribute__((ext_vector_type(4)));

__global__ __launch_bounds__(448) void sub2_plane_kernel(
    const float* __restrict__ in1,
    const float* __restrict__ in2,
    float* __restrict__ out)
{
    const int b  = blockIdx.x;      // 0..12543 == output plane index
    const int nc = b / KK;          // compiler magic-div
    const int p  = b - nc * KK;     // 0..48
    const int dy = p / 7 - 3;
    const int dx = p % 7 - 3;

    const float* a_pl = in1 + (size_t)nc * PLANE;
    const float* b_pl = in2 + (size_t)nc * PLANE;
    float*       o_pl = out + (size_t)b * PLANE;

    const int tid = threadIdx.x;        // 0..447 (7 waves)
    const int y0  = tid / 28;           // 0..15
    const int x0  = (tid % 28) * 4;     // 0..108

    #pragma unroll
    for (int k = 0; k < 7; ++k) {
        const int y = y0 + k * 16;
        const f4 a = *reinterpret_cast<const f4*>(a_pl + y * HW + x0);

        float w[4] = {0.f, 0.f, 0.f, 0.f};
        const int iy = y + dy;
        if (iy >= 0 && iy < HW) {
            const float* row = b_pl + iy * HW;
            const int xb = x0 + dx;
            #pragma unroll
            for (int m = 0; m < 4; ++m) {
                const int xx = xb + m;
                const int xc = xx < 0 ? 0 : (xx > HW - 1 ? HW - 1 : xx);
                const float v = row[xc];                // clamped addr, safe
                w[m] = (xx >= 0 && xx < HW) ? v : 0.f;  // mask pad region
            }
        }

        f4 r;
        r.x = a.x - w[0];
        r.y = a.y - w[1];
        r.z = a.z - w[2];
        r.w = a.w - w[3];
        *reinterpret_cast<f4*>(o_pl + y * HW + x0) = r;
    }
}

extern "C" void kernel_launch(void* const* d_in, const int* in_sizes, int n_in,
                              void* d_out, int out_size, void* d_ws, size_t ws_size,
                              hipStream_t stream) {
    const float* in1 = (const float*)d_in[0];
    const float* in2 = (const float*)d_in[1];
    float* out = (float*)d_out;

    const int blocks = KK * NC_TOT;   // 12544 planes, b = nc*49 + p
    sub2_plane_kernel<<<blocks, 448, 0, stream>>>(in1, in2, out);
}

// Round 4
// 128.587 us; speedup vs baseline: 1.9366x; 1.9366x over previous
//
#include <hip/hip_runtime.h>

// out[n,c,p,y,x] = in1[n,c,y,x] - zpad(in2)[n,c, y+i-3, x+j-3],  p = i*7+j
// N=8, C=32, H=W=112 -> out [8,32,49,112,112] fp32 (629 MB).
//
// R3 = R0 skeleton (best: 134.7 us; thread owns (nc,y,x4) and all 49 p-plane
// stores -> max store ILP, 1KB coalesced wave stores) + LDS staging of the
// in2 tile. Rationale: R0's 629 MB write-allocate stream thrashes the 4MB/XCD
// L2, so in2 re-reads (up to 49x reuse) fall to L3 over Infinity Fabric and
// compete with the write stream. Staging in2 once in LDS makes the steady
// state a pure write stream. R1/R2 plane-per-block restructures regressed
// (172/249 us) -> reverted; nt stores regressed -> plain stores.

#define HW     112
#define PLANE  12544        // 112*112
#define KK     49
#define NC_TOT 256          // 8*32
#define YB     16           // output rows per block
#define LROWS  22           // YB + 6 halo rows
#define LDSW   132          // LDS row pitch in floats: [0..7]=0pad, [8..119]=x, [120..131]=0pad

typedef float f4 __attribute__((ext_vector_type(4)));

__global__ __launch_bounds__(448) void sub2_kernel(
    const float* __restrict__ in1,
    const float* __restrict__ in2,
    float* __restrict__ out)
{
    __shared__ float smem[LROWS * LDSW];   // 11616 B

    const int b   = blockIdx.x;            // b = nc*7 + yb  (nc-major, like R0)
    const int nc  = b / 7;
    const int yb  = b - nc * 7;
    const int y0  = yb * YB;
    const int tid = threadIdx.x;

    // zero all of smem (726 f4 stores across 448 threads)
    {
        const f4 z = {0.f, 0.f, 0.f, 0.f};
        for (int idx = tid; idx < (LROWS * LDSW) / 4; idx += 448)
            reinterpret_cast<f4*>(smem)[idx] = z;
    }
    __syncthreads();

    // stage in2 rows [y0-3, y0+18] into smem data region (28 f4 per row)
    const float* b_pl = in2 + (size_t)nc * PLANE;
    for (int idx = tid; idx < LROWS * 28; idx += 448) {
        const int r  = idx / 28;
        const int c  = idx - r * 28;
        const int gy = y0 - 3 + r;
        if (gy >= 0 && gy < HW) {
            *reinterpret_cast<f4*>(&smem[r * LDSW + 8 + 4 * c]) =
                *reinterpret_cast<const f4*>(b_pl + gy * HW + 4 * c);
        }
    }
    __syncthreads();

    const int yl = tid / 28;               // 0..15
    const int x0 = (tid - yl * 28) * 4;    // 0..108
    const int y  = y0 + yl;

    const f4 a = *reinterpret_cast<const f4*>(
        in1 + (size_t)nc * PLANE + y * HW + x0);
    float* o_base = out + (size_t)nc * KK * PLANE + (size_t)y * HW + x0;

    #pragma unroll
    for (int i = 0; i < 7; ++i) {
        // window floats x0-4 .. x0+11 (16B-aligned ds_read_b128 x4)
        const float* wr = &smem[(yl + i) * LDSW + 4 + x0];
        const f4 w0 = *reinterpret_cast<const f4*>(wr);
        const f4 w1 = *reinterpret_cast<const f4*>(wr + 4);
        const f4 w2 = *reinterpret_cast<const f4*>(wr + 8);
        const f4 w3 = *reinterpret_cast<const f4*>(wr + 12);
        float wf[16];
        wf[0]=w0.x;  wf[1]=w0.y;  wf[2]=w0.z;  wf[3]=w0.w;
        wf[4]=w1.x;  wf[5]=w1.y;  wf[6]=w1.z;  wf[7]=w1.w;
        wf[8]=w2.x;  wf[9]=w2.y;  wf[10]=w2.z; wf[11]=w2.w;
        wf[12]=w3.x; wf[13]=w3.y; wf[14]=w3.z; wf[15]=w3.w;

        #pragma unroll
        for (int j = 0; j < 7; ++j) {
            f4 r;
            r.x = a.x - wf[j + 1];
            r.y = a.y - wf[j + 2];
            r.z = a.z - wf[j + 3];
            r.w = a.w - wf[j + 4];
            *reinterpret_cast<f4*>(o_base + (size_t)(i * 7 + j) * PLANE) = r;
        }
    }
}

extern "C" void kernel_launch(void* const* d_in, const int* in_sizes, int n_in,
                              void* d_out, int out_size, void* d_ws, size_t ws_size,
                              hipStream_t stream) {
    const float* in1 = (const float*)d_in[0];
    const float* in2 = (const float*)d_in[1];
    float* out = (float*)d_out;

    const int blocks = NC_TOT * 7;   // 1792, b = nc*7 + yb
    sub2_kernel<<<blocks, 448, 0, stream>>>(in1, in2, out);
}